// Round 11
// baseline (678.118 us; speedup 1.0000x reference)
//
#include <hip/hip_runtime.h>
#include <hip/hip_bf16.h>

#define N_NODES 100000
#define N_EDGES 1600000
#define D 128
#define N_LAYERS 4
#define LN_EPS 1e-5f
#define NB_SCAN ((N_NODES + 255) / 256)   // 391
#define NSLICE 8
#define NODES_PER_SLICE (N_NODES / NSLICE)  // 12500
#define FILL_CHUNKS 256
#define EDGES_PER_CHUNK (N_EDGES / FILL_CHUNKS)  // 6250
#define AGG_CHUNKS ((N_NODES + 127) / 128)  // 782

typedef _Float16 half8 __attribute__((ext_vector_type(8)));
typedef _Float16 half4v __attribute__((ext_vector_type(4)));
typedef float f32x4 __attribute__((ext_vector_type(4)));

// ---------------- CSR build ----------------
__global__ void k_count(const int* __restrict__ ei, int* __restrict__ counts) {
    int e = blockIdx.x * blockDim.x + threadIdx.x;
    if (e < N_EDGES) {
        int dst = __builtin_nontemporal_load(ei + N_EDGES + e);
        atomicAdd(&counts[dst], 1);
    }
}

__global__ __launch_bounds__(256) void k_scan1(const int* __restrict__ counts,
                                               int* __restrict__ row_start,
                                               int* __restrict__ blocksums,
                                               float* __restrict__ dinv) {
    __shared__ int buf[256];
    int tid = threadIdx.x;
    int i = blockIdx.x * 256 + tid;
    int c = (i < N_NODES) ? counts[i] : 0;
    if (i < N_NODES) dinv[i] = rsqrtf((float)c + 1.0f);
    buf[tid] = c;
    __syncthreads();
    #pragma unroll
    for (int off = 1; off < 256; off <<= 1) {
        int v = (tid >= off) ? buf[tid - off] : 0;
        __syncthreads();
        buf[tid] += v;
        __syncthreads();
    }
    if (i < N_NODES) row_start[i] = buf[tid] - c;
    if (tid == 255) blocksums[blockIdx.x] = buf[255];
}

__global__ __launch_bounds__(512) void k_scan2(const int* __restrict__ blocksums,
                                               int* __restrict__ blockoff) {
    __shared__ int buf[512];
    int tid = threadIdx.x;
    int c = (tid < NB_SCAN) ? blocksums[tid] : 0;
    buf[tid] = c;
    __syncthreads();
    #pragma unroll
    for (int off = 1; off < 512; off <<= 1) {
        int v = (tid >= off) ? buf[tid - off] : 0;
        __syncthreads();
        buf[tid] += v;
        __syncthreads();
    }
    if (tid < NB_SCAN) blockoff[tid] = buf[tid] - c;
}

__global__ __launch_bounds__(256) void k_scan3(const int* __restrict__ blockoff,
                                               int* __restrict__ row_start,
                                               int* __restrict__ cursor) {
    int i = blockIdx.x * 256 + threadIdx.x;
    if (i < N_NODES) {
        int rs = row_start[i] + blockoff[blockIdx.x];
        row_start[i] = rs;
        cursor[i] = rs;
    }
}

// XCD-sliced CSR fill (round-10 best: 2048 blocks, plain loads)
__global__ __launch_bounds__(256) void k_fillx(const int* __restrict__ ei,
                                               int* __restrict__ cursor,
                                               int* __restrict__ col) {
    int wg = blockIdx.x;
    int slice = wg & (NSLICE - 1);
    int chunk = wg >> 3;
    int lo = slice * NODES_PER_SLICE;
    int hi = lo + NODES_PER_SLICE;
    int e0 = chunk * EDGES_PER_CHUNK;
    int e1 = e0 + EDGES_PER_CHUNK;
    for (int e = e0 + threadIdx.x; e < e1; e += 256) {
        int dst = ei[N_EDGES + e];
        if (dst >= lo && dst < hi) {
            int src = ei[e];
            int p = atomicAdd(&cursor[dst], 1);
            col[p] = src;
        }
    }
}

// ---------------- weight prep ----------------
__global__ __launch_bounds__(256) void k_prep_w(const float* __restrict__ Ws,
                                                _Float16* __restrict__ WT) {
    int idx = blockIdx.x * 256 + threadIdx.x;
    int l = idx >> 14;
    int k = (idx >> 7) & 127;
    int n = idx & 127;
    WT[(size_t)l * D * D + (size_t)n * D + k] = (_Float16)Ws[(size_t)l * D * D + (size_t)k * D + n];
}

// -------- MFMA GEMM: hwS[s][row][16] = dinv[row] * (H @ W) sliced --------
// output slice s = wn*4 + ni is a 3.2MB table (fits one XCD L2) -> the agg
// gather for slice s stays XCD-local.
__global__ __launch_bounds__(256) void k_gemm(const _Float16* __restrict__ H,
                                              const _Float16* __restrict__ WT,
                                              const float* __restrict__ dinv,
                                              _Float16* __restrict__ hwS) {
    int t = threadIdx.x;
    int wave = t >> 6;
    int lane = t & 63;
    int wm = wave & 1, wn = wave >> 1;
    int m0 = blockIdx.x * 64 + wm * 32;
    int n0 = wn * 64;
    int lr = lane & 15;
    int kg = lane >> 4;

    f32x4 acc[2][4] = {};

    const half8* Hr[2];
    #pragma unroll
    for (int mi = 0; mi < 2; mi++) {
        int row = m0 + mi * 16 + lr;
        row = row < N_NODES ? row : N_NODES - 1;
        Hr[mi] = (const half8*)(H + (size_t)row * D);
    }
    const half8* Wr[4];
    #pragma unroll
    for (int ni = 0; ni < 4; ni++)
        Wr[ni] = (const half8*)(WT + (size_t)(n0 + ni * 16 + lr) * D);

    #pragma unroll
    for (int ks = 0; ks < 4; ks++) {
        half8 a0 = Hr[0][ks * 4 + kg];
        half8 a1 = Hr[1][ks * 4 + kg];
        half8 b0 = Wr[0][ks * 4 + kg];
        half8 b1 = Wr[1][ks * 4 + kg];
        half8 b2 = Wr[2][ks * 4 + kg];
        half8 b3 = Wr[3][ks * 4 + kg];
        acc[0][0] = __builtin_amdgcn_mfma_f32_16x16x32_f16(a0, b0, acc[0][0], 0, 0, 0);
        acc[0][1] = __builtin_amdgcn_mfma_f32_16x16x32_f16(a0, b1, acc[0][1], 0, 0, 0);
        acc[0][2] = __builtin_amdgcn_mfma_f32_16x16x32_f16(a0, b2, acc[0][2], 0, 0, 0);
        acc[0][3] = __builtin_amdgcn_mfma_f32_16x16x32_f16(a0, b3, acc[0][3], 0, 0, 0);
        acc[1][0] = __builtin_amdgcn_mfma_f32_16x16x32_f16(a1, b0, acc[1][0], 0, 0, 0);
        acc[1][1] = __builtin_amdgcn_mfma_f32_16x16x32_f16(a1, b1, acc[1][1], 0, 0, 0);
        acc[1][2] = __builtin_amdgcn_mfma_f32_16x16x32_f16(a1, b2, acc[1][2], 0, 0, 0);
        acc[1][3] = __builtin_amdgcn_mfma_f32_16x16x32_f16(a1, b3, acc[1][3], 0, 0, 0);
    }

    #pragma unroll
    for (int mi = 0; mi < 2; mi++) {
        #pragma unroll
        for (int r = 0; r < 4; r++) {
            int row = m0 + mi * 16 + kg * 4 + r;
            if (row < N_NODES) {
                float dv = dinv[row];
                #pragma unroll
                for (int ni = 0; ni < 4; ni++) {
                    size_t sb = (size_t)(wn * 4 + ni) * N_NODES * 16;
                    hwS[sb + (size_t)row * 16 + lr] = (_Float16)(acc[mi][ni][r] * dv);
                }
            }
        }
    }
}

// layer-0 variant: reads f32 x directly
__global__ __launch_bounds__(256) void k_gemm0(const float* __restrict__ X,
                                               const _Float16* __restrict__ WT,
                                               const float* __restrict__ dinv,
                                               _Float16* __restrict__ hwS) {
    int t = threadIdx.x;
    int wave = t >> 6;
    int lane = t & 63;
    int wm = wave & 1, wn = wave >> 1;
    int m0 = blockIdx.x * 64 + wm * 32;
    int n0 = wn * 64;
    int lr = lane & 15;
    int kg = lane >> 4;

    f32x4 acc[2][4] = {};

    const float4* Xr[2];
    #pragma unroll
    for (int mi = 0; mi < 2; mi++) {
        int row = m0 + mi * 16 + lr;
        row = row < N_NODES ? row : N_NODES - 1;
        Xr[mi] = (const float4*)(X + (size_t)row * D);
    }
    const half8* Wr[4];
    #pragma unroll
    for (int ni = 0; ni < 4; ni++)
        Wr[ni] = (const half8*)(WT + (size_t)(n0 + ni * 16 + lr) * D);

    #pragma unroll
    for (int ks = 0; ks < 4; ks++) {
        half8 a0, a1;
        {
            float4 p = Xr[0][(ks * 4 + kg) * 2];
            float4 q = Xr[0][(ks * 4 + kg) * 2 + 1];
            a0[0] = (_Float16)p.x; a0[1] = (_Float16)p.y; a0[2] = (_Float16)p.z; a0[3] = (_Float16)p.w;
            a0[4] = (_Float16)q.x; a0[5] = (_Float16)q.y; a0[6] = (_Float16)q.z; a0[7] = (_Float16)q.w;
            float4 r = Xr[1][(ks * 4 + kg) * 2];
            float4 s = Xr[1][(ks * 4 + kg) * 2 + 1];
            a1[0] = (_Float16)r.x; a1[1] = (_Float16)r.y; a1[2] = (_Float16)r.z; a1[3] = (_Float16)r.w;
            a1[4] = (_Float16)s.x; a1[5] = (_Float16)s.y; a1[6] = (_Float16)s.z; a1[7] = (_Float16)s.w;
        }
        half8 b0 = Wr[0][ks * 4 + kg];
        half8 b1 = Wr[1][ks * 4 + kg];
        half8 b2 = Wr[2][ks * 4 + kg];
        half8 b3 = Wr[3][ks * 4 + kg];
        acc[0][0] = __builtin_amdgcn_mfma_f32_16x16x32_f16(a0, b0, acc[0][0], 0, 0, 0);
        acc[0][1] = __builtin_amdgcn_mfma_f32_16x16x32_f16(a0, b1, acc[0][1], 0, 0, 0);
        acc[0][2] = __builtin_amdgcn_mfma_f32_16x16x32_f16(a0, b2, acc[0][2], 0, 0, 0);
        acc[0][3] = __builtin_amdgcn_mfma_f32_16x16x32_f16(a0, b3, acc[0][3], 0, 0, 0);
        acc[1][0] = __builtin_amdgcn_mfma_f32_16x16x32_f16(a1, b0, acc[1][0], 0, 0, 0);
        acc[1][1] = __builtin_amdgcn_mfma_f32_16x16x32_f16(a1, b1, acc[1][1], 0, 0, 0);
        acc[1][2] = __builtin_amdgcn_mfma_f32_16x16x32_f16(a1, b2, acc[1][2], 0, 0, 0);
        acc[1][3] = __builtin_amdgcn_mfma_f32_16x16x32_f16(a1, b3, acc[1][3], 0, 0, 0);
    }

    #pragma unroll
    for (int mi = 0; mi < 2; mi++) {
        #pragma unroll
        for (int r = 0; r < 4; r++) {
            int row = m0 + mi * 16 + kg * 4 + r;
            if (row < N_NODES) {
                float dv = dinv[row];
                #pragma unroll
                for (int ni = 0; ni < 4; ni++) {
                    size_t sb = (size_t)(wn * 4 + ni) * N_NODES * 16;
                    hwS[sb + (size_t)row * 16 + lr] = (_Float16)(acc[mi][ni][r] * dv);
                }
            }
        }
    }
}

// ------------- agg phase 1: per-slice gather (XCD-local L2 table) -------------
// slice = blockIdx&7 rides XCD round-robin; slice table = 3.2MB < 4MB L2.
// 2 lanes x half8 per (node,slice); 128 nodes/block.
__global__ __launch_bounds__(256) void k_aggs(const _Float16* __restrict__ hwS,
                                              const int* __restrict__ row_start,
                                              const int* __restrict__ counts,
                                              const int* __restrict__ col,
                                              _Float16* __restrict__ part) {
    int s = blockIdx.x & 7;
    int chunk = blockIdx.x >> 3;
    int t = threadIdx.x;
    int n = chunk * 128 + (t >> 1);
    if (n >= N_NODES) return;
    int pl = t & 1;

    const half8* tblS = (const half8*)hwS + (size_t)s * (N_NODES * 2) + pl;
    int start = row_start[n], cnt = counts[n];
    const int* cw = col + start;
    half8 vself = tblS[(size_t)n * 2];

    float a[8] = {};
    int j = 0;
    for (; j + 4 <= cnt; j += 4) {
        int i0 = cw[j], i1 = cw[j + 1], i2 = cw[j + 2], i3 = cw[j + 3];
        half8 v0 = tblS[(size_t)i0 * 2];
        half8 v1 = tblS[(size_t)i1 * 2];
        half8 v2 = tblS[(size_t)i2 * 2];
        half8 v3 = tblS[(size_t)i3 * 2];
        #pragma unroll
        for (int d = 0; d < 8; d++)
            a[d] += (float)v0[d] + (float)v1[d] + (float)v2[d] + (float)v3[d];
    }
    for (; j < cnt; j++) {
        half8 v = tblS[(size_t)cw[j] * 2];
        #pragma unroll
        for (int d = 0; d < 8; d++) a[d] += (float)v[d];
    }
    #pragma unroll
    for (int d = 0; d < 8; d++) a[d] += (float)vself[d];

    half8 o;
    #pragma unroll
    for (int d = 0; d < 8; d++) o[d] = (_Float16)a[d];
    ((half8*)(part + (size_t)n * D + s * 16))[pl] = o;
}

// ------------- agg phase 2: bias + LN + ReLU (coalesced rows) -------------
__global__ __launch_bounds__(256) void k_ln(const _Float16* __restrict__ part,
                                            const float* __restrict__ dinv,
                                            const float* __restrict__ b,
                                            const float* __restrict__ gamma,
                                            const float* __restrict__ beta,
                                            _Float16* __restrict__ hout,
                                            float* __restrict__ fout,
                                            int last) {
    int hwv = threadIdx.x >> 5;
    int sl  = threadIdx.x & 31;
    int n = blockIdx.x * 8 + hwv;
    if (n >= N_NODES) return;

    half4v p = ((const half4v*)(part + (size_t)n * D))[sl];
    float dn = dinv[n];
    float4 bv = *(const float4*)(b + 4 * sl);
    float a0 = (float)p[0] * dn + bv.x;
    float a1 = (float)p[1] * dn + bv.y;
    float a2 = (float)p[2] * dn + bv.z;
    float a3 = (float)p[3] * dn + bv.w;

    float s = a0 + a1 + a2 + a3;
    #pragma unroll
    for (int off = 16; off >= 1; off >>= 1) s += __shfl_xor(s, off);
    float mean = s * (1.0f / 128.0f);
    float c0 = a0 - mean, c1 = a1 - mean, c2 = a2 - mean, c3 = a3 - mean;
    float q = c0 * c0 + c1 * c1 + c2 * c2 + c3 * c3;
    #pragma unroll
    for (int off = 16; off >= 1; off >>= 1) q += __shfl_xor(q, off);
    float rstd = rsqrtf(q * (1.0f / 128.0f) + LN_EPS);

    float4 gv = *(const float4*)(gamma + 4 * sl);
    float4 tv = *(const float4*)(beta  + 4 * sl);
    float o0 = fmaxf(c0 * rstd * gv.x + tv.x, 0.f);
    float o1 = fmaxf(c1 * rstd * gv.y + tv.y, 0.f);
    float o2 = fmaxf(c2 * rstd * gv.z + tv.z, 0.f);
    float o3 = fmaxf(c3 * rstd * gv.w + tv.w, 0.f);

    if (last) {
        f32x4 o4; o4[0] = o0; o4[1] = o1; o4[2] = o2; o4[3] = o3;
        __builtin_nontemporal_store(o4, (f32x4*)(fout + (size_t)n * D) + sl);
    } else {
        half4v o;
        o[0] = (_Float16)o0; o[1] = (_Float16)o1;
        o[2] = (_Float16)o2; o[3] = (_Float16)o3;
        ((half4v*)(hout + (size_t)n * D))[sl] = o;
    }
}

extern "C" void kernel_launch(void* const* d_in, const int* in_sizes, int n_in,
                              void* d_out, int out_size, void* d_ws, size_t ws_size,
                              hipStream_t stream) {
    const float* x      = (const float*)d_in[0];
    const int*   ei     = (const int*)d_in[1];
    const float* Ws     = (const float*)d_in[2];
    const float* bs     = (const float*)d_in[3];
    const float* gammas = (const float*)d_in[4];
    const float* betas  = (const float*)d_in[5];
    float* out = (float*)d_out;

    char* ws = (char*)d_ws;
    int*   counts    = (int*)ws;   ws += (size_t)N_NODES * 4;
    int*   row_start = (int*)ws;   ws += (size_t)N_NODES * 4;
    int*   cursor    = (int*)ws;   ws += (size_t)N_NODES * 4;
    float* dinv      = (float*)ws; ws += (size_t)N_NODES * 4;
    int*   blocksums = (int*)ws;   ws += 512 * 4;
    int*   blockoff  = (int*)ws;   ws += 512 * 4;
    int*   col       = (int*)ws;   ws += (size_t)N_EDGES * 4;
    _Float16* h      = (_Float16*)ws; ws += (size_t)N_NODES * D * 2;
    _Float16* hwS    = (_Float16*)ws; ws += (size_t)NSLICE * N_NODES * 16 * 2;
    _Float16* part   = (_Float16*)ws; ws += (size_t)N_NODES * D * 2;
    _Float16* wt     = (_Float16*)ws; ws += (size_t)N_LAYERS * D * D * 2;

    (void)hipMemsetAsync(counts, 0, (size_t)N_NODES * 4, stream);
    k_count<<<(N_EDGES + 255) / 256, 256, 0, stream>>>(ei, counts);
    k_scan1<<<NB_SCAN, 256, 0, stream>>>(counts, row_start, blocksums, dinv);
    k_scan2<<<1, 512, 0, stream>>>(blocksums, blockoff);
    k_scan3<<<NB_SCAN, 256, 0, stream>>>(blockoff, row_start, cursor);
    k_fillx<<<NSLICE * FILL_CHUNKS, 256, 0, stream>>>(ei, cursor, col);
    k_prep_w<<<(N_LAYERS * D * D) / 256, 256, 0, stream>>>(Ws, wt);

    for (int l = 0; l < N_LAYERS; l++) {
        if (l == 0)
            k_gemm0<<<(N_NODES + 63) / 64, 256, 0, stream>>>(x, wt, dinv, hwS);
        else
            k_gemm<<<(N_NODES + 63) / 64, 256, 0, stream>>>(h, wt + (size_t)l * D * D, dinv, hwS);
        k_aggs<<<AGG_CHUNKS * NSLICE, 256, 0, stream>>>(hwS, row_start, counts, col, part);
        int last = (l == N_LAYERS - 1) ? 1 : 0;
        k_ln<<<(N_NODES + 7) / 8, 256, 0, stream>>>(part, dinv, bs + l * D,
                                                    gammas + l * D, betas + l * D,
                                                    h, out, last);
    }
}